// Round 10
// baseline (273.616 us; speedup 1.0000x reference)
//
#include <hip/hip_runtime.h>
#include <hip/hip_bf16.h>
#include <stdint.h>

#define B_    2
#define S_    4096
#define DM_   2048
#define H_    16
#define D_    128
#define M_TOT (B_ * S_)     // 8192
#define N_TOT (3 * DM_)     // 6144
#define K_TOT DM_           // 2048

typedef __attribute__((ext_vector_type(8))) short  short8;
typedef __attribute__((ext_vector_type(4))) float  f32x4;
typedef unsigned short ushort_t;

__device__ __forceinline__ unsigned short f2bf(float f) {
    union { float f; unsigned u; } u; u.f = f;
    unsigned r = u.u + 0x7fffu + ((u.u >> 16) & 1u);
    return (unsigned short)(r >> 16);
}
__device__ __forceinline__ float bf2f(unsigned short s) {
    union { unsigned u; float f; } u; u.u = ((unsigned)s) << 16;
    return u.f;
}

__device__ __forceinline__ void gload_lds16(const void* g, void* l) {
    __builtin_amdgcn_global_load_lds(
        (const __attribute__((address_space(1))) void*)g,
        (__attribute__((address_space(3))) void*)l,
        16, 0, 0);
}

// ---------------- cast fp32 -> bf16 (vectorized) ----------------
__global__ void cast_f32_bf16(const float* __restrict__ src,
                              unsigned short* __restrict__ dst, int n4) {
    int i = blockIdx.x * blockDim.x + threadIdx.x;
    int stride = gridDim.x * blockDim.x;
    for (; i < n4; i += stride) {
        float4 v = ((const float4*)src)[i];
        ushort4 o;
        o.x = f2bf(v.x); o.y = f2bf(v.y); o.z = f2bf(v.z); o.w = f2bf(v.w);
        ((ushort4*)dst)[i] = o;
    }
}

// ---------------- QKV GEMM: 256x256, 2-phase K-tile (merged from R9's 4) ----
// C[M][N] = A[M][K] * B[N][K]^T (+bias), bf16 in, bf16 out.
// 512 thr = 8 waves (2M x 4N); per-wave output 128x64 (8x4 frags of 16x16).
// LDS: 2 buffers x (A[256][64] + B[256][64]) bf16 = 128 KiB, st_16x32 swizzle.
// R9 (4-phase) measured 51% MfmaUtil; model: 2483 MFMA + ~1540 LDS-drain
// + ~400 barrier cy/tile. Merging to 2 phases halves barrier count and
// drain exposure while keeping EVERY proven invariant:
//  - same-phase read->consume with compiler-precise lgkmcnt (no forced drains)
//  - stage targets only regions read >=1 phase earlier (barrier between)
//  - VM6 ONCE per tile at Ph2-end; steady-state entry = 6 outstanding
//    (= next tile's G1-G3), VM6 drains only loads >=1 phase (~2000cy) old.
//   Ph1: rd b01,a1,b23 (16) | st G4(T+1)      | mfma a1x(b01,b23) 32
//   Ph2: rd a2 (8)          | st G1,G2,G3(T+2)| mfma a2x(b01,b23) 32 | vmcnt(6)

#define BKT   64
#define NKT   (K_TOT / BKT)   // 32 K-tiles
#define ABUF  16384           // ushort offset of B-tile within a buffer
#define BUF1  32768           // ushort offset of buffer 1

#define PB() do { asm volatile("" ::: "memory");                               \
                  __builtin_amdgcn_s_barrier();                                \
                  asm volatile("" ::: "memory"); } while (0)
#define VM6()   asm volatile("s_waitcnt vmcnt(6)" ::: "memory")
#define VM0()   asm volatile("s_waitcnt vmcnt(0)" ::: "memory")
#define SP1()   __builtin_amdgcn_s_setprio(1)
#define SP0()   __builtin_amdgcn_s_setprio(0)
#define NOSTAGE do {} while (0)
#define NOVM    do {} while (0)

// stage one 16x64 LDS block (2 gload_lds) of A or B at k-offset K0
#define STAGE_A(BO, K0, ABLK) do {                                              \
    const ushort_t* s_ = aStage + (size_t)(ABLK) * (16 * K_TOT) + (K0);         \
    gload_lds16(s_,      &lds[(BO) + (ABLK) * 1024]);                           \
    gload_lds16(s_ + 32, &lds[(BO) + (ABLK) * 1024 + 512]);                     \
} while (0)
#define STAGE_B(BO, K0, BBLK) do {                                              \
    const ushort_t* s_ = bStage + (size_t)(BBLK) * (16 * K_TOT) + (K0);         \
    gload_lds16(s_,      &lds[(BO) + ABUF + (BBLK) * 1024]);                    \
    gload_lds16(s_ + 32, &lds[(BO) + ABUF + (BBLK) * 1024 + 512]);              \
} while (0)

#define READ_A(DST, I0, BO) do { _Pragma("unroll")                              \
    for (int i = 0; i < 4; ++i) { _Pragma("unroll")                             \
    for (int ks = 0; ks < 2; ++ks)                                              \
        DST[i][ks] = *(const short8*)&lds[(BO) + (wm * 8 + (I0) + i) * 1024 + ks * 512 + innerRd]; \
    } } while (0)

#define READ_B(DST, N0, BO) do { _Pragma("unroll")                              \
    for (int n = 0; n < 2; ++n) { _Pragma("unroll")                             \
    for (int ks = 0; ks < 2; ++ks)                                              \
        DST[n][ks] = *(const short8*)&lds[(BO) + ABUF + (wn * 4 + (N0) + n) * 1024 + ks * 512 + innerRd]; \
    } } while (0)

// ks OUTERMOST: same-acc dependency distance = 8
#define MQ(AR, I0, BR, N0) do { _Pragma("unroll")                               \
    for (int ks = 0; ks < 2; ++ks) { _Pragma("unroll")                          \
    for (int i = 0; i < 4; ++i) { _Pragma("unroll")                             \
    for (int n = 0; n < 2; ++n)                                                 \
        acc[(I0) + i][(N0) + n] = __builtin_amdgcn_mfma_f32_16x16x32_bf16(      \
            AR[i][ks], BR[n][ks], acc[(I0) + i][(N0) + n], 0, 0, 0);            \
    } } } while (0)

#define KTILE2(BO, S1, S2, VM_STMT) do {                                        \
    /* Ph1 */ READ_B(b01, 0, BO); READ_A(a1, 0, BO); READ_B(b23, 2, BO); S1;    \
    PB();                                                                       \
    SP1(); MQ(a1, 0, b01, 0); MQ(a1, 0, b23, 2); SP0(); PB();                   \
    /* Ph2 */ READ_A(a2, 4, BO); S2;                                            \
    PB();                                                                       \
    SP1(); MQ(a2, 4, b01, 0); MQ(a2, 4, b23, 2); SP0(); VM_STMT; PB();          \
} while (0)

__global__ __launch_bounds__(512, 2) void gemm_qkv(
    const ushort_t* __restrict__ A,   // [M_TOT][K_TOT] bf16
    const ushort_t* __restrict__ Bm,  // [N_TOT][K_TOT] bf16 (Wq;Wk;Wv)
    const float* __restrict__ bq, const float* __restrict__ bk,
    const float* __restrict__ bv,
    ushort_t* __restrict__ C)         // [M_TOT][N_TOT] bf16
{
    __shared__ __align__(16) ushort_t lds[65536];   // 128 KiB

    // XCD-aware bijective swizzle (768 % 8 == 0)
    const int nwg = gridDim.x;                  // 768
    const int cpx = nwg >> 3;                   // 96
    const int bid = blockIdx.x;
    const int swz = (bid & 7) * cpx + (bid >> 3);
    const int ntile = N_TOT / 256;              // 24
    const int tm = swz / ntile;
    const int tn = swz % ntile;
    const int tmRow = tm * 256, tnRow = tn * 256;

    const int tid  = threadIdx.x;
    const int w    = tid >> 6;
    const int lane = tid & 63;
    const int wm   = w >> 2, wn = w & 3;        // 2 x 4 wave grid

    // staging block groups: G1(a1-blocks)=wA, G4(a2)=wA+4, G2(b01)=wB, G3(b23)=wB+2
    const int wA = w + (w & 4);
    const int wB = ((w >> 1) << 2) | (w & 1);

    // staging source (inverse-swizzle): lane L -> row L>>2, col ((L&3)*8)^((L>>5)<<4)
    const int rL     = lane >> 2;
    const int cSwzSt = ((lane & 3) * 8) ^ (((lane >> 5) & 1) << 4);
    const ushort_t* aStage = A  + (size_t)(tmRow + rL) * K_TOT + cSwzSt;
    const ushort_t* bStage = Bm + (size_t)(tnRow + rL) * K_TOT + cSwzSt;

    // ds_read fragment offset within a subtile (swizzled)
    const int rA      = lane & 15;
    const int innerRd = (rA * 32 + (lane >> 4) * 8) ^ (((rA >> 3) & 1) << 4);

    f32x4  acc[8][4] = {};
    short8 a1[4][2], a2[4][2], b01[2][2], b23[2][2];

    // prologue: tile0 G1-G4 -> buf0 (8 loads); tile1 G1,G2,G3 -> buf1 (6).
    // VM6: 14 outstanding -> drains the 8 oldest = ALL of tile0 (fixes R4/R9's
    // latent T0-G4 race); leaves tile1's 6 in flight = steady-state entry.
    STAGE_A(0, 0, wA);  STAGE_B(0, 0, wB);  STAGE_B(0, 0, wB + 2);  STAGE_A(0, 0, wA + 4);
    STAGE_A(BUF1, BKT, wA); STAGE_B(BUF1, BKT, wB); STAGE_B(BUF1, BKT, wB + 2);
    VM6();
    PB();

    // steady loop: tiles 0..29; tile T stages G4(T+1) at Ph1, G1-G3(T+2) at Ph2
    for (int kt = 0; kt < NKT - 2; kt += 2) {
        KTILE2(0,
               STAGE_A(BUF1, (size_t)(kt + 1) * BKT, wA + 4),            // G4(T+1)
               { STAGE_A(0, (size_t)(kt + 2) * BKT, wA);                 // G1(T+2)
                 STAGE_B(0, (size_t)(kt + 2) * BKT, wB);                 // G2(T+2)
                 STAGE_B(0, (size_t)(kt + 2) * BKT, wB + 2); },          // G3(T+2)
               VM6());
        KTILE2(BUF1,
               STAGE_A(0, (size_t)(kt + 2) * BKT, wA + 4),               // G4(T+2)
               { STAGE_A(BUF1, (size_t)(kt + 3) * BKT, wA);              // G1(T+3)
                 STAGE_B(BUF1, (size_t)(kt + 3) * BKT, wB);              // G2(T+3)
                 STAGE_B(BUF1, (size_t)(kt + 3) * BKT, wB + 2); },       // G3(T+3)
               VM6());
    }
    // epilogue: tile 30 (stage G4(31); VM0 drains it), tile 31 (no staging)
    KTILE2(0,
           STAGE_A(BUF1, (size_t)(NKT - 1) * BKT, wA + 4),               // G4(31)
           NOSTAGE,
           VM0());
    KTILE2(BUF1, NOSTAGE, NOSTAGE, NOVM);

    // ---- epilogue: repack through LDS for coalesced 16B stores ----
    {
        ushort_t* ldsW = &lds[w * 1152];
        const int colBase = tnRow + wn * 64;
        const float* bias = (colBase < 2048) ? bq : (colBase < 4096) ? bk : bv;
        const int rowBase = tmRow + wm * 128;
        float bval[4];
#pragma unroll
        for (int n = 0; n < 4; ++n)
            bval[n] = bias[(colBase + n * 16 + (lane & 15)) & 2047];
#pragma unroll
        for (int i = 0; i < 8; ++i) {
#pragma unroll
            for (int n = 0; n < 4; ++n)
#pragma unroll
                for (int r = 0; r < 4; ++r)
                    ldsW[((lane >> 4) * 4 + r) * 72 + n * 16 + (lane & 15)] =
                        f2bf(acc[i][n][r] + bval[n]);
            asm volatile("s_waitcnt lgkmcnt(0)" ::: "memory");  // writes -> readable
#pragma unroll
            for (int half = 0; half < 2; ++half) {
                const int row = half * 8 + (lane >> 3);
                short8 v = *(const short8*)&ldsW[row * 72 + (lane & 7) * 8];
                *(short8*)&C[(size_t)(rowBase + i * 16 + row) * N_TOT +
                             colBase + (lane & 7) * 8] = v;
            }
            asm volatile("s_waitcnt lgkmcnt(0)" ::: "memory");  // reads done before next i
        }
    }
}

// ---------------- per-position heads-attention ----------------
#define LSTR 132   // padded fp32 row stride (breaks stride-128 bank conflicts)

__global__ __launch_bounds__(256) void attn_kernel(
    const ushort_t* __restrict__ QKV,  // [M_TOT][N_TOT] bf16
    float* __restrict__ out)           // [B][S][DM] fp32, scattered layout
{
    __shared__ __align__(16) float Qs[H_ * LSTR];
    __shared__ __align__(16) float Ks[H_ * LSTR];
    __shared__ __align__(16) float Vs[H_ * LSTR];

    const int pos = blockIdx.x;
    const int b   = pos >> 12;
    const int s   = pos & 4095;
    const int tid = threadIdx.x;
    const int lane = tid & 63;
    const ushort_t* row = QKV + (size_t)pos * N_TOT;

    {
        const int r  = tid >> 4;
        const int d0 = (tid & 15) * 8;
        short8 q = *(const short8*)(row +        r * 128 + d0);
        short8 k = *(const short8*)(row + 2048 + r * 128 + d0);
        short8 v = *(const short8*)(row + 4096 + r * 128 + d0);
#pragma unroll
        for (int j = 0; j < 8; ++j) {
            Qs[r * LSTR + d0 + j] = bf2f((unsigned short)q[j]);
            Ks[r * LSTR + d0 + j] = bf2f((unsigned short)k[j]);
            Vs[r * LSTR + d0 + j] = bf2f((unsigned short)v[j]);
        }
    }
    __syncthreads();

    const int h = tid >> 4;
    const int t = tid & 15;
    float sc = 0.f;
    {
        const float* qp = &Qs[h * LSTR];
        const float* kp = &Ks[t * LSTR];
#pragma unroll
        for (int d = 0; d < 128; d += 4) {
            float4 qv = *(const float4*)(qp + d);
            float4 kv = *(const float4*)(kp + d);
            sc += qv.x * kv.x + qv.y * kv.y + qv.z * kv.z + qv.w * kv.w;
        }
    }
    sc *= 0.08838834764831845f;   // 1/sqrt(128)

    float mx = sc;
#pragma unroll
    for (int o = 1; o < 16; o <<= 1) mx = fmaxf(mx, __shfl_xor(mx, o, 64));
    float e = __expf(sc - mx);
    float sm = e;
#pragma unroll
    for (int o = 1; o < 16; o <<= 1) sm += __shfl_xor(sm, o, 64);
    const float attn = e / sm;

    float o8[8] = {0.f, 0.f, 0.f, 0.f, 0.f, 0.f, 0.f, 0.f};
#pragma unroll
    for (int tt = 0; tt < 16; ++tt) {
        const float aw = __shfl(attn, (lane & 48) | tt, 64);
        const float* vp = &Vs[tt * LSTR + t * 8];
        float4 v0 = *(const float4*)(vp);
        float4 v1 = *(const float4*)(vp + 4);
        o8[0] += aw * v0.x; o8[1] += aw * v0.y; o8[2] += aw * v0.z; o8[3] += aw * v0.w;
        o8[4] += aw * v1.x; o8[5] += aw * v1.y; o8[6] += aw * v1.z; o8[7] += aw * v1.w;
    }

    const int orow = h * 256 + (s >> 4);
    const int ocol = (s & 15) * 128 + t * 8;
    float* op = out + ((size_t)b * S_ + orow) * DM_ + ocol;
    float4 w0 = { o8[0], o8[1], o8[2], o8[3] };
    float4 w1 = { o8[4], o8[5], o8[6], o8[7] };
    *(float4*)(op)     = w0;
    *(float4*)(op + 4) = w1;
}

// ---------------- launch ----------------
extern "C" void kernel_launch(void* const* d_in, const int* in_sizes, int n_in,
                              void* d_out, int out_size, void* d_ws, size_t ws_size,
                              hipStream_t stream) {
    const float* x  = (const float*)d_in[0];
    const float* Wq = (const float*)d_in[1];
    const float* bq = (const float*)d_in[2];
    const float* Wk = (const float*)d_in[3];
    const float* bk = (const float*)d_in[4];
    const float* Wv = (const float*)d_in[5];
    const float* bv = (const float*)d_in[6];
    float* out = (float*)d_out;

    char* ws = (char*)d_ws;
    unsigned short* xb  = (unsigned short*)ws;                       // 33,554,432 B
    unsigned short* Wb  = (unsigned short*)(ws + 33554432);          // 25,165,824 B
    unsigned short* qkv = (unsigned short*)(ws + 58720256);          // 100,663,296 B

    cast_f32_bf16<<<4096, 256, 0, stream>>>(x,  xb,                 (M_TOT * K_TOT) / 4);
    cast_f32_bf16<<<2048, 256, 0, stream>>>(Wq, Wb,                 (DM_ * DM_) / 4);
    cast_f32_bf16<<<2048, 256, 0, stream>>>(Wk, Wb + DM_ * DM_,     (DM_ * DM_) / 4);
    cast_f32_bf16<<<2048, 256, 0, stream>>>(Wv, Wb + 2 * DM_ * DM_, (DM_ * DM_) / 4);

    gemm_qkv<<<(M_TOT / 256) * (N_TOT / 256), 512, 0, stream>>>(xb, Wb, bq, bk, bv, qkv);

    attn_kernel<<<M_TOT, 256, 0, stream>>>(qkv, out);
}

// Round 11
// 241.506 us; speedup vs baseline: 1.1330x; 1.1330x over previous
//
#include <hip/hip_runtime.h>
#include <hip/hip_bf16.h>
#include <stdint.h>

#define B_    2
#define S_    4096
#define DM_   2048
#define H_    16
#define D_    128
#define M_TOT (B_ * S_)     // 8192
#define N_TOT (3 * DM_)     // 6144
#define K_TOT DM_           // 2048

typedef __attribute__((ext_vector_type(8))) short  short8;
typedef __attribute__((ext_vector_type(4))) float  f32x4;
typedef unsigned short ushort_t;

__device__ __forceinline__ unsigned short f2bf(float f) {
    union { float f; unsigned u; } u; u.f = f;
    unsigned r = u.u + 0x7fffu + ((u.u >> 16) & 1u);
    return (unsigned short)(r >> 16);
}
__device__ __forceinline__ float bf2f(unsigned short s) {
    union { unsigned u; float f; } u; u.u = ((unsigned)s) << 16;
    return u.f;
}

__device__ __forceinline__ void gload_lds16(const void* g, void* l) {
    __builtin_amdgcn_global_load_lds(
        (const __attribute__((address_space(1))) void*)g,
        (__attribute__((address_space(3))) void*)l,
        16, 0, 0);
}

// ---------------- cast fp32 -> bf16 (vectorized) ----------------
__global__ void cast_f32_bf16(const float* __restrict__ src,
                              unsigned short* __restrict__ dst, int n4) {
    int i = blockIdx.x * blockDim.x + threadIdx.x;
    int stride = gridDim.x * blockDim.x;
    for (; i < n4; i += stride) {
        float4 v = ((const float4*)src)[i];
        ushort4 o;
        o.x = f2bf(v.x); o.y = f2bf(v.y); o.z = f2bf(v.z); o.w = f2bf(v.w);
        ((ushort4*)dst)[i] = o;
    }
}

// ---------------- QKV GEMM: R9 4-phase, mid-phase barrier REMOVED -----------
// C[M][N] = A[M][K] * B[N][K]^T (+bias), bf16 in, bf16 out.
// 512 thr = 8 waves (2M x 4N); per-wave output 128x64 (8x4 frags of 16x16).
// LDS: 2 buffers x (A[256][64] + B[256][64]) bf16 = 128 KiB, st_16x32 swizzle.
// R9 (51% MfmaUtil) had {reads; stage; BARRIER; MFMA; BARRIER} per phase:
// the first barrier forced all 8 waves to drain reads in LOCKSTEP — no
// wave's MFMA could cover another's drain. Hazard re-derivation: the only
// cross-wave hazard (stage@q vs read@q-1 of same region) is already closed
// by the END-of-phase barrier: B's q-1 reads complete (lgkm, before B's own
// MFMA) before B passes barrier(q-1), which A must pass before issuing its
// q-stage. So ONE barrier per phase suffices; waves now enter MFMA as soon
// as their OWN operands land -> SIMD-mate overlap (drain under MFMA), and
// setprio(1) finally has role-divergent waves to arbitrate.
//   P1: rd a1,b01(cur) | st G4(T+1)->next | mfma a1xb01 | bar
//   P2: rd b23(cur)    | st G1(T+2)->cur  | mfma a1xb23 | bar
//   P3: rd a2(cur)     | st G2(T+2)->cur  | mfma a2xb01 | bar
//   P4:                | st G3(T+2)->cur  | mfma a2xb23 | vmcnt(6) | bar
// Staging ledger byte-identical to R9 (proven): every stage targets a
// region last read >=1 phase (+barrier) earlier; VM6 once per tile only
// drains loads >=4 phases old.

#define BKT   64
#define NKT   (K_TOT / BKT)   // 32 K-tiles
#define ABUF  16384           // ushort offset of B-tile within a buffer
#define BUF1  32768           // ushort offset of buffer 1

#define PB() do { asm volatile("" ::: "memory");                               \
                  __builtin_amdgcn_s_barrier();                                \
                  asm volatile("" ::: "memory"); } while (0)
#define VM6()   asm volatile("s_waitcnt vmcnt(6)" ::: "memory")
#define VM0()   asm volatile("s_waitcnt vmcnt(0)" ::: "memory")
#define SP1()   __builtin_amdgcn_s_setprio(1)
#define SP0()   __builtin_amdgcn_s_setprio(0)
#define NOSTAGE do {} while (0)
#define NOVM    do {} while (0)

// stage one 16x64 LDS block (2 gload_lds) of A or B at k-offset K0
#define STAGE_A(BO, K0, ABLK) do {                                              \
    const ushort_t* s_ = aStage + (size_t)(ABLK) * (16 * K_TOT) + (K0);         \
    gload_lds16(s_,      &lds[(BO) + (ABLK) * 1024]);                           \
    gload_lds16(s_ + 32, &lds[(BO) + (ABLK) * 1024 + 512]);                     \
} while (0)
#define STAGE_B(BO, K0, BBLK) do {                                              \
    const ushort_t* s_ = bStage + (size_t)(BBLK) * (16 * K_TOT) + (K0);         \
    gload_lds16(s_,      &lds[(BO) + ABUF + (BBLK) * 1024]);                    \
    gload_lds16(s_ + 32, &lds[(BO) + ABUF + (BBLK) * 1024 + 512]);              \
} while (0)

#define READ_A(DST, I0, BO) do { _Pragma("unroll")                              \
    for (int i = 0; i < 4; ++i) { _Pragma("unroll")                             \
    for (int ks = 0; ks < 2; ++ks)                                              \
        DST[i][ks] = *(const short8*)&lds[(BO) + (wm * 8 + (I0) + i) * 1024 + ks * 512 + innerRd]; \
    } } while (0)

#define READ_B(DST, N0, BO) do { _Pragma("unroll")                              \
    for (int n = 0; n < 2; ++n) { _Pragma("unroll")                             \
    for (int ks = 0; ks < 2; ++ks)                                              \
        DST[n][ks] = *(const short8*)&lds[(BO) + ABUF + (wn * 4 + (N0) + n) * 1024 + ks * 512 + innerRd]; \
    } } while (0)

// ks OUTERMOST: same-acc dependency distance = 8
#define MQ(AR, I0, BR, N0) do { _Pragma("unroll")                               \
    for (int ks = 0; ks < 2; ++ks) { _Pragma("unroll")                          \
    for (int i = 0; i < 4; ++i) { _Pragma("unroll")                             \
    for (int n = 0; n < 2; ++n)                                                 \
        acc[(I0) + i][(N0) + n] = __builtin_amdgcn_mfma_f32_16x16x32_bf16(      \
            AR[i][ks], BR[n][ks], acc[(I0) + i][(N0) + n], 0, 0, 0);            \
    } } } while (0)

#define KTILE(BO, S1, S2, S3, S4, VM_STMT) do {                                 \
    /* P1 */ READ_A(a1, 0, BO); READ_B(b01, 0, BO); S1;                         \
    SP1(); MQ(a1, 0, b01, 0); SP0(); PB();                                      \
    /* P2 */ READ_B(b23, 2, BO); S2;                                            \
    SP1(); MQ(a1, 0, b23, 2); SP0(); PB();                                      \
    /* P3 */ READ_A(a2, 4, BO); S3;                                             \
    SP1(); MQ(a2, 4, b01, 0); SP0(); PB();                                      \
    /* P4 */ S4;                                                                \
    SP1(); MQ(a2, 4, b23, 2); SP0(); VM_STMT; PB();                             \
} while (0)

__global__ __launch_bounds__(512, 2) void gemm_qkv(
    const ushort_t* __restrict__ A,   // [M_TOT][K_TOT] bf16
    const ushort_t* __restrict__ Bm,  // [N_TOT][K_TOT] bf16 (Wq;Wk;Wv)
    const float* __restrict__ bq, const float* __restrict__ bk,
    const float* __restrict__ bv,
    ushort_t* __restrict__ C)         // [M_TOT][N_TOT] bf16
{
    __shared__ __align__(16) ushort_t lds[65536];   // 128 KiB

    // XCD-aware bijective swizzle (768 % 8 == 0)
    const int nwg = gridDim.x;                  // 768
    const int cpx = nwg >> 3;                   // 96
    const int bid = blockIdx.x;
    const int swz = (bid & 7) * cpx + (bid >> 3);
    const int ntile = N_TOT / 256;              // 24
    const int tm = swz / ntile;
    const int tn = swz % ntile;
    const int tmRow = tm * 256, tnRow = tn * 256;

    const int tid  = threadIdx.x;
    const int w    = tid >> 6;
    const int lane = tid & 63;
    const int wm   = w >> 2, wn = w & 3;        // 2 x 4 wave grid

    // staging block groups: G1(a1-blocks)=wA, G4(a2)=wA+4, G2(b01)=wB, G3(b23)=wB+2
    const int wA = w + (w & 4);
    const int wB = ((w >> 1) << 2) | (w & 1);

    // staging source (inverse-swizzle): lane L -> row L>>2, col ((L&3)*8)^((L>>5)<<4)
    const int rL     = lane >> 2;
    const int cSwzSt = ((lane & 3) * 8) ^ (((lane >> 5) & 1) << 4);
    const ushort_t* aStage = A  + (size_t)(tmRow + rL) * K_TOT + cSwzSt;
    const ushort_t* bStage = Bm + (size_t)(tnRow + rL) * K_TOT + cSwzSt;

    // ds_read fragment offset within a subtile (swizzled)
    const int rA      = lane & 15;
    const int innerRd = (rA * 32 + (lane >> 4) * 8) ^ (((rA >> 3) & 1) << 4);

    f32x4  acc[8][4] = {};
    short8 a1[4][2], a2[4][2], b01[2][2], b23[2][2];

    // prologue: tile0 G1-G4 -> buf0 (8 loads); tile1 G1,G2,G3 -> buf1 (6).
    // VM6: 14 outstanding -> drains the 8 oldest = ALL of tile0 (incl. G4;
    // fixes R9's latent T0-G4 race); leaves tile1's 6 in flight.
    STAGE_A(0, 0, wA);  STAGE_B(0, 0, wB);  STAGE_B(0, 0, wB + 2);  STAGE_A(0, 0, wA + 4);
    STAGE_A(BUF1, BKT, wA); STAGE_B(BUF1, BKT, wB); STAGE_B(BUF1, BKT, wB + 2);
    VM6();
    PB();

    // steady loop: tiles 0..29 (staging schedule identical to R9/round-4)
    for (int kt = 0; kt < NKT - 2; kt += 2) {
        KTILE(0,
              STAGE_A(BUF1, (size_t)(kt + 1) * BKT, wA + 4),   // G4(T+1)
              STAGE_A(0,    (size_t)(kt + 2) * BKT, wA),       // G1(T+2)
              STAGE_B(0,    (size_t)(kt + 2) * BKT, wB),       // G2(T+2)
              STAGE_B(0,    (size_t)(kt + 2) * BKT, wB + 2),   // G3(T+2)
              VM6());
        KTILE(BUF1,
              STAGE_A(0,    (size_t)(kt + 2) * BKT, wA + 4),   // G4(T+2)
              STAGE_A(BUF1, (size_t)(kt + 3) * BKT, wA),       // G1(T+3)
              STAGE_B(BUF1, (size_t)(kt + 3) * BKT, wB),       // G2(T+3)
              STAGE_B(BUF1, (size_t)(kt + 3) * BKT, wB + 2),   // G3(T+3)
              VM6());
    }
    // epilogue: tile 30 (stage G4(31); VM0 drains it), tile 31 (no staging)
    KTILE(0,
          STAGE_A(BUF1, (size_t)(NKT - 1) * BKT, wA + 4),      // G4(31)
          NOSTAGE, NOSTAGE, NOSTAGE,
          VM0());
    KTILE(BUF1, NOSTAGE, NOSTAGE, NOSTAGE, NOSTAGE, NOVM);

    // ---- epilogue: repack through LDS for coalesced 16B stores ----
    {
        ushort_t* ldsW = &lds[w * 1152];
        const int colBase = tnRow + wn * 64;
        const float* bias = (colBase < 2048) ? bq : (colBase < 4096) ? bk : bv;
        const int rowBase = tmRow + wm * 128;
        float bval[4];
#pragma unroll
        for (int n = 0; n < 4; ++n)
            bval[n] = bias[(colBase + n * 16 + (lane & 15)) & 2047];
#pragma unroll
        for (int i = 0; i < 8; ++i) {
#pragma unroll
            for (int n = 0; n < 4; ++n)
#pragma unroll
                for (int r = 0; r < 4; ++r)
                    ldsW[((lane >> 4) * 4 + r) * 72 + n * 16 + (lane & 15)] =
                        f2bf(acc[i][n][r] + bval[n]);
            asm volatile("s_waitcnt lgkmcnt(0)" ::: "memory");  // writes -> readable
#pragma unroll
            for (int half = 0; half < 2; ++half) {
                const int row = half * 8 + (lane >> 3);
                short8 v = *(const short8*)&ldsW[row * 72 + (lane & 7) * 8];
                *(short8*)&C[(size_t)(rowBase + i * 16 + row) * N_TOT +
                             colBase + (lane & 7) * 8] = v;
            }
            asm volatile("s_waitcnt lgkmcnt(0)" ::: "memory");  // reads done before next i
        }
    }
}

// ---------------- per-position heads-attention ----------------
#define LSTR 132   // padded fp32 row stride (breaks stride-128 bank conflicts)

__global__ __launch_bounds__(256) void attn_kernel(
    const ushort_t* __restrict__ QKV,  // [M_TOT][N_TOT] bf16
    float* __restrict__ out)           // [B][S][DM] fp32, scattered layout
{
    __shared__ __align__(16) float Qs[H_ * LSTR];
    __shared__ __align__(16) float Ks[H_ * LSTR];
    __shared__ __align__(16) float Vs[H_ * LSTR];

    const int pos = blockIdx.x;
    const int b   = pos >> 12;
    const int s   = pos & 4095;
    const int tid = threadIdx.x;
    const int lane = tid & 63;
    const ushort_t* row = QKV + (size_t)pos * N_TOT;

    {
        const int r  = tid >> 4;
        const int d0 = (tid & 15) * 8;
        short8 q = *(const short8*)(row +        r * 128 + d0);
        short8 k = *(const short8*)(row + 2048 + r * 128 + d0);
        short8 v = *(const short8*)(row + 4096 + r * 128 + d0);
#pragma unroll
        for (int j = 0; j < 8; ++j) {
            Qs[r * LSTR + d0 + j] = bf2f((unsigned short)q[j]);
            Ks[r * LSTR + d0 + j] = bf2f((unsigned short)k[j]);
            Vs[r * LSTR + d0 + j] = bf2f((unsigned short)v[j]);
        }
    }
    __syncthreads();

    const int h = tid >> 4;
    const int t = tid & 15;
    float sc = 0.f;
    {
        const float* qp = &Qs[h * LSTR];
        const float* kp = &Ks[t * LSTR];
#pragma unroll
        for (int d = 0; d < 128; d += 4) {
            float4 qv = *(const float4*)(qp + d);
            float4 kv = *(const float4*)(kp + d);
            sc += qv.x * kv.x + qv.y * kv.y + qv.z * kv.z + qv.w * kv.w;
        }
    }
    sc *= 0.08838834764831845f;   // 1/sqrt(128)

    float mx = sc;
#pragma unroll
    for (int o = 1; o < 16; o <<= 1) mx = fmaxf(mx, __shfl_xor(mx, o, 64));
    float e = __expf(sc - mx);
    float sm = e;
#pragma unroll
    for (int o = 1; o < 16; o <<= 1) sm += __shfl_xor(sm, o, 64);
    const float attn = e / sm;

    float o8[8] = {0.f, 0.f, 0.f, 0.f, 0.f, 0.f, 0.f, 0.f};
#pragma unroll
    for (int tt = 0; tt < 16; ++tt) {
        const float aw = __shfl(attn, (lane & 48) | tt, 64);
        const float* vp = &Vs[tt * LSTR + t * 8];
        float4 v0 = *(const float4*)(vp);
        float4 v1 = *(const float4*)(vp + 4);
        o8[0] += aw * v0.x; o8[1] += aw * v0.y; o8[2] += aw * v0.z; o8[3] += aw * v0.w;
        o8[4] += aw * v1.x; o8[5] += aw * v1.y; o8[6] += aw * v1.z; o8[7] += aw * v1.w;
    }

    const int orow = h * 256 + (s >> 4);
    const int ocol = (s & 15) * 128 + t * 8;
    float* op = out + ((size_t)b * S_ + orow) * DM_ + ocol;
    float4 w0 = { o8[0], o8[1], o8[2], o8[3] };
    float4 w1 = { o8[4], o8[5], o8[6], o8[7] };
    *(float4*)(op)     = w0;
    *(float4*)(op + 4) = w1;
}

// ---------------- launch ----------------
extern "C" void kernel_launch(void* const* d_in, const int* in_sizes, int n_in,
                              void* d_out, int out_size, void* d_ws, size_t ws_size,
                              hipStream_t stream) {
    const float* x  = (const float*)d_in[0];
    const float* Wq = (const float*)d_in[1];
    const float* bq = (const float*)d_in[2];
    const float* Wk = (const float*)d_in[3];
    const float* bk = (const float*)d_in[4];
    const float* Wv = (const float*)d_in[5];
    const float* bv = (const float*)d_in[6];
    float* out = (float*)d_out;

    char* ws = (char*)d_ws;
    unsigned short* xb  = (unsigned short*)ws;                       // 33,554,432 B
    unsigned short* Wb  = (unsigned short*)(ws + 33554432);          // 25,165,824 B
    unsigned short* qkv = (unsigned short*)(ws + 58720256);          // 100,663,296 B

    cast_f32_bf16<<<4096, 256, 0, stream>>>(x,  xb,                 (M_TOT * K_TOT) / 4);
    cast_f32_bf16<<<2048, 256, 0, stream>>>(Wq, Wb,                 (DM_ * DM_) / 4);
    cast_f32_bf16<<<2048, 256, 0, stream>>>(Wk, Wb + DM_ * DM_,     (DM_ * DM_) / 4);
    cast_f32_bf16<<<2048, 256, 0, stream>>>(Wv, Wb + 2 * DM_ * DM_, (DM_ * DM_) / 4);

    gemm_qkv<<<(M_TOT / 256) * (N_TOT / 256), 512, 0, stream>>>(xb, Wb, bq, bk, bv, qkv);

    attn_kernel<<<M_TOT, 256, 0, stream>>>(qkv, out);
}